// Round 1
// baseline (954.405 us; speedup 1.0000x reference)
//
#include <hip/hip_runtime.h>
#include <math.h>

// Problem constants (fixed by the reference)
#define NN   20000
#define EE   320000
#define DIN  128
#define KK   8
#define HH   64
#define NEG  0.01f

// ---------------------------------------------------------------------------
// Helpers
// ---------------------------------------------------------------------------
__device__ __forceinline__ float wave_sum(float v) {
#pragma unroll
  for (int m = 1; m < 64; m <<= 1) v += __shfl_xor(v, m, 64);
  return v;
}

// ---------------------------------------------------------------------------
// K0: V[d][k] = sum_h W_enc[d, k*64+h] * attn_l[k,h]   (128x8, trivial)
// ---------------------------------------------------------------------------
__global__ __launch_bounds__(256) void k_v(const float* __restrict__ W_enc,
                                           const float* __restrict__ attn_l,
                                           float* __restrict__ V) {
  int gid = blockIdx.x * 256 + threadIdx.x;
  if (gid < DIN * KK) {
    int d = gid >> 3, k = gid & 7;
    float acc = 0.f;
#pragma unroll 8
    for (int h = 0; h < HH; ++h)
      acc += W_enc[(long)d * 512 + k * 64 + h] * attn_l[k * 64 + h];
    V[d * 8 + k] = acc;
  }
}

// ---------------------------------------------------------------------------
// K1: er[n][k] = node_feat[n,:] . W_r[k,:]
// ---------------------------------------------------------------------------
__global__ __launch_bounds__(256) void k_er(const float* __restrict__ node_feat,
                                            const float* __restrict__ W_r,
                                            float* __restrict__ er) {
  __shared__ __align__(16) float4 wr4[KK * 32];
  int tid = threadIdx.x;
  if (tid < 256) wr4[tid] = ((const float4*)W_r)[tid];
  __syncthreads();
  int gid = blockIdx.x * 256 + tid;
  int n = gid >> 3, k = gid & 7;
  if (n < NN) {
    const float4* nf4 = (const float4*)node_feat + (long)n * 32;
    float acc = 0.f;
#pragma unroll
    for (int i = 0; i < 32; ++i) {
      float4 a = nf4[i], b = wr4[k * 32 + i];
      acc += a.x * b.x + a.y * b.y + a.z * b.z + a.w * b.w;
    }
    er[gid] = acc;
  }
}

// ---------------------------------------------------------------------------
// K2: per edge: x[e,:] = mean_L edge_feat[e]; e_log[e,k] = leaky(x.V + er[dst])
// One wave per edge, 4 edges per wave (loop). Grid = EE/16 blocks of 256.
// ---------------------------------------------------------------------------
__global__ __launch_bounds__(256) void k_mean_logits(
    const float* __restrict__ edge_feat, const float* __restrict__ V,
    const float* __restrict__ er, const int* __restrict__ dst,
    float* __restrict__ x, float* __restrict__ e_log) {
  int lane = threadIdx.x & 63;
  int gw = (blockIdx.x * 256 + (int)threadIdx.x) >> 6;  // global wave id
  // per-lane V fragment: rows d0 = 2*lane, 2*lane+1 (8 floats each)
  const float4* V4 = (const float4*)V;
  float4 va0 = V4[lane * 4 + 0];  // V[2l][0..3]
  float4 va1 = V4[lane * 4 + 1];  // V[2l][4..7]
  float4 vb0 = V4[lane * 4 + 2];  // V[2l+1][0..3]
  float4 vb1 = V4[lane * 4 + 3];  // V[2l+1][4..7]
  const float2* ef2 = (const float2*)edge_feat;
#pragma unroll 1
  for (int t = 0; t < 4; ++t) {
    int e = gw * 4 + t;
    if (e >= EE) break;
    long b = (long)e * 192;  // 3*128 floats = 192 float2
    float2 r0 = ef2[b + lane];
    float2 r1 = ef2[b + 64 + lane];
    float2 r2 = ef2[b + 128 + lane];
    float x0 = (r0.x + r1.x + r2.x) * (1.f / 3.f);
    float x1 = (r0.y + r1.y + r2.y) * (1.f / 3.f);
    ((float2*)x)[(long)e * 64 + lane] = make_float2(x0, x1);
    float p0 = x0 * va0.x + x1 * vb0.x;
    float p1 = x0 * va0.y + x1 * vb0.y;
    float p2 = x0 * va0.z + x1 * vb0.z;
    float p3 = x0 * va0.w + x1 * vb0.w;
    float p4 = x0 * va1.x + x1 * vb1.x;
    float p5 = x0 * va1.y + x1 * vb1.y;
    float p6 = x0 * va1.z + x1 * vb1.z;
    float p7 = x0 * va1.w + x1 * vb1.w;
    p0 = wave_sum(p0); p1 = wave_sum(p1); p2 = wave_sum(p2); p3 = wave_sum(p3);
    p4 = wave_sum(p4); p5 = wave_sum(p5); p6 = wave_sum(p6); p7 = wave_sum(p7);
    if (lane == 0) {
      int dv = dst[e];
      float4 ea = ((const float4*)er)[dv * 2 + 0];
      float4 eb = ((const float4*)er)[dv * 2 + 1];
      float z0 = p0 + ea.x, z1 = p1 + ea.y, z2 = p2 + ea.z, z3 = p3 + ea.w;
      float z4 = p4 + eb.x, z5 = p5 + eb.y, z6 = p6 + eb.z, z7 = p7 + eb.w;
      float4 o0 = make_float4(z0 > 0.f ? z0 : NEG * z0, z1 > 0.f ? z1 : NEG * z1,
                              z2 > 0.f ? z2 : NEG * z2, z3 > 0.f ? z3 : NEG * z3);
      float4 o1 = make_float4(z4 > 0.f ? z4 : NEG * z4, z5 > 0.f ? z5 : NEG * z5,
                              z6 > 0.f ? z6 : NEG * z6, z7 > 0.f ? z7 : NEG * z7);
      ((float4*)e_log)[(long)e * 2 + 0] = o0;
      ((float4*)e_log)[(long)e * 2 + 1] = o1;
    }
  }
}

// ---------------------------------------------------------------------------
// K3: histogram of dst
// ---------------------------------------------------------------------------
__global__ __launch_bounds__(256) void k_hist(const int* __restrict__ dst,
                                              int* __restrict__ counts) {
  int e = blockIdx.x * 256 + threadIdx.x;
  if (e < EE) atomicAdd(&counts[dst[e]], 1);
}

// ---------------------------------------------------------------------------
// K4: exclusive scan of counts -> offs[0..NN], cursor copy. Single block 1024.
// ---------------------------------------------------------------------------
__global__ __launch_bounds__(1024) void k_scan(const int* __restrict__ counts,
                                               int* __restrict__ offs,
                                               int* __restrict__ cursor) {
  __shared__ int wsum[16], wpre[16];
  __shared__ int running;
  int tid = threadIdx.x, lane = tid & 63, wid = tid >> 6;
  if (tid == 0) running = 0;
  __syncthreads();
  for (int base = 0; base < NN; base += 1024) {
    int i = base + tid;
    int v = (i < NN) ? counts[i] : 0;
    int incl = v;
#pragma unroll
    for (int off = 1; off < 64; off <<= 1) {
      int t = __shfl_up(incl, off, 64);
      if (lane >= off) incl += t;
    }
    if (lane == 63) wsum[wid] = incl;
    __syncthreads();
    if (tid < 16) {
      int sv = wsum[tid];
#pragma unroll
      for (int off = 1; off < 16; off <<= 1) {
        int t = __shfl_up(sv, off, 64);
        if (tid >= off) sv += t;
      }
      wpre[tid] = sv;
    }
    __syncthreads();
    int wexcl = (wid == 0) ? 0 : wpre[wid - 1];
    int excl = running + wexcl + (incl - v);
    if (i < NN) { offs[i] = excl; cursor[i] = excl; }
    int tot = wpre[15];
    __syncthreads();
    if (tid == 0) running += tot;
    __syncthreads();
  }
  if (threadIdx.x == 0) offs[NN] = running;
}

// ---------------------------------------------------------------------------
// K5: scatter edge ids into CSR
// ---------------------------------------------------------------------------
__global__ __launch_bounds__(256) void k_fill(const int* __restrict__ dst,
                                              int* __restrict__ cursor,
                                              int* __restrict__ elist) {
  int e = blockIdx.x * 256 + threadIdx.x;
  if (e < EE) {
    int p = atomicAdd(&cursor[dst[e]], 1);
    elist[p] = e;
  }
}

// ---------------------------------------------------------------------------
// K6: per-node segmented softmax + weighted aggregation:
//     y[n,k,d] = sum_{e in n} a[e,k] * x[e,d]
// One block (256 thr) per node. Accumulators in registers (4 k per thread).
// ---------------------------------------------------------------------------
__global__ __launch_bounds__(256) void k_agg(const int* __restrict__ offs,
                                             const int* __restrict__ elist,
                                             const float* __restrict__ e_log,
                                             const float* __restrict__ x,
                                             float* __restrict__ y) {
  __shared__ float maxs[8], invs[8];
  __shared__ float red[4][8];
  __shared__ __align__(16) float4 xs4[32 * 32];   // 32 edges x 128 floats
  __shared__ __align__(16) float wbuf[32 * 8];    // 32 edges x 8 weights
  int n = blockIdx.x;
  int tid = threadIdx.x, lane = tid & 63, wid = tid >> 6;
  int start = offs[n], end = offs[n + 1];

  // ---- pass A: per-k max ----
  float m[8];
#pragma unroll
  for (int k = 0; k < 8; ++k) m[k] = -3.4e38f;
  for (int i = start + tid; i < end; i += 256) {
    long e = elist[i];
    float4 a = ((const float4*)e_log)[e * 2 + 0];
    float4 b = ((const float4*)e_log)[e * 2 + 1];
    m[0] = fmaxf(m[0], a.x); m[1] = fmaxf(m[1], a.y);
    m[2] = fmaxf(m[2], a.z); m[3] = fmaxf(m[3], a.w);
    m[4] = fmaxf(m[4], b.x); m[5] = fmaxf(m[5], b.y);
    m[6] = fmaxf(m[6], b.z); m[7] = fmaxf(m[7], b.w);
  }
#pragma unroll
  for (int k = 0; k < 8; ++k) {
#pragma unroll
    for (int mm = 1; mm < 64; mm <<= 1) m[k] = fmaxf(m[k], __shfl_xor(m[k], mm, 64));
  }
  if (lane == 0) {
#pragma unroll
    for (int k = 0; k < 8; ++k) red[wid][k] = m[k];
  }
  __syncthreads();
  if (tid < 8)
    maxs[tid] = fmaxf(fmaxf(red[0][tid], red[1][tid]), fmaxf(red[2][tid], red[3][tid]));
  __syncthreads();
  float mk[8];
#pragma unroll
  for (int k = 0; k < 8; ++k) mk[k] = maxs[k];

  // ---- pass B: per-k sum of exp ----
  float s[8];
#pragma unroll
  for (int k = 0; k < 8; ++k) s[k] = 0.f;
  for (int i = start + tid; i < end; i += 256) {
    long e = elist[i];
    float4 a = ((const float4*)e_log)[e * 2 + 0];
    float4 b = ((const float4*)e_log)[e * 2 + 1];
    s[0] += __expf(a.x - mk[0]); s[1] += __expf(a.y - mk[1]);
    s[2] += __expf(a.z - mk[2]); s[3] += __expf(a.w - mk[3]);
    s[4] += __expf(b.x - mk[4]); s[5] += __expf(b.y - mk[5]);
    s[6] += __expf(b.z - mk[6]); s[7] += __expf(b.w - mk[7]);
  }
#pragma unroll
  for (int k = 0; k < 8; ++k) s[k] = wave_sum(s[k]);
  if (lane == 0) {
#pragma unroll
    for (int k = 0; k < 8; ++k) red[wid][k] = s[k];
  }
  __syncthreads();
  if (tid < 8) {
    float tot = red[0][tid] + red[1][tid] + red[2][tid] + red[3][tid];
    invs[tid] = tot > 0.f ? 1.f / tot : 0.f;
  }
  __syncthreads();

  // ---- pass C: weighted aggregation, 32-edge batches staged in LDS ----
  float acc0 = 0.f, acc1 = 0.f, acc2 = 0.f, acc3 = 0.f;
  int d = tid & 127, kg = tid >> 7;  // kg in {0,1}: k = kg*4 + i
  const float* xs = (const float*)xs4;
  for (int base = start; base < end; base += 32) {
    int nb = min(32, end - base);
    for (int j = tid; j < nb * 32; j += 256) {
      long e = elist[base + (j >> 5)];
      xs4[j] = ((const float4*)x)[e * 32 + (j & 31)];
    }
    if (tid < nb * 8) {
      long e = elist[base + (tid >> 3)];
      int k = tid & 7;
      wbuf[tid] = __expf(e_log[e * 8 + k] - maxs[k]) * invs[k];
    }
    __syncthreads();
    for (int j = 0; j < nb; ++j) {
      float xv = xs[j * 128 + d];
      float4 wv = *(const float4*)&wbuf[j * 8 + kg * 4];
      acc0 += wv.x * xv; acc1 += wv.y * xv; acc2 += wv.z * xv; acc3 += wv.w * xv;
    }
    __syncthreads();
  }
  float* yp = y + (long)n * 1024 + kg * 512 + d;
  yp[0]   = acc0;
  yp[128] = acc1;
  yp[256] = acc2;
  yp[384] = acc3;
}

// ---------------------------------------------------------------------------
// K7: out[n,k,h] = sum_d y[n,k,d] * W_enc[d, k*64+h]
// Block: 32 nodes x 64 h for one k. 256 threads, 8 outputs each.
// ---------------------------------------------------------------------------
__global__ __launch_bounds__(256) void k_out(const float* __restrict__ y,
                                             const float* __restrict__ W_enc,
                                             float* __restrict__ out) {
  __shared__ __align__(16) float ys[32 * 128];  // 16 KB
  __shared__ __align__(16) float ws[128 * 64];  // 32 KB, natural [d][h]
  int k = blockIdx.y, n0 = blockIdx.x * 32;
  int tid = threadIdx.x;
  for (int i = tid; i < 32 * 128; i += 256) {
    int r = i >> 7, dd = i & 127;
    ys[i] = y[(long)(n0 + r) * 1024 + k * 128 + dd];
  }
  for (int i = tid; i < 128 * 64; i += 256) {
    int h = i & 63, dd = i >> 6;
    ws[dd * 64 + h] = W_enc[(long)dd * 512 + k * 64 + h];
  }
  __syncthreads();
  int h = tid & 63, rg = tid >> 6;
  float acc[8] = {0.f, 0.f, 0.f, 0.f, 0.f, 0.f, 0.f, 0.f};
  for (int d4 = 0; d4 < 32; ++d4) {
    float w0 = ws[(d4 * 4 + 0) * 64 + h];
    float w1 = ws[(d4 * 4 + 1) * 64 + h];
    float w2 = ws[(d4 * 4 + 2) * 64 + h];
    float w3 = ws[(d4 * 4 + 3) * 64 + h];
#pragma unroll
    for (int i = 0; i < 8; ++i) {
      float4 yv = *(const float4*)&ys[(rg * 8 + i) * 128 + d4 * 4];
      acc[i] += yv.x * w0 + yv.y * w1 + yv.z * w2 + yv.w * w3;
    }
  }
#pragma unroll
  for (int i = 0; i < 8; ++i)
    out[(long)(n0 + rg * 8 + i) * 512 + k * 64 + h] = acc[i];
}

// ---------------------------------------------------------------------------
// launch
// ---------------------------------------------------------------------------
extern "C" void kernel_launch(void* const* d_in, const int* in_sizes, int n_in,
                              void* d_out, int out_size, void* d_ws, size_t ws_size,
                              hipStream_t stream) {
  const float* node_feat = (const float*)d_in[0];
  const float* edge_feat = (const float*)d_in[1];
  const float* W_enc     = (const float*)d_in[2];
  const float* attn_l    = (const float*)d_in[3];
  const float* W_r       = (const float*)d_in[4];
  const int*   dst       = (const int*)d_in[5];
  float* out = (float*)d_out;

  // workspace carve-up (~259 MB total)
  char* ws = (char*)d_ws;
  size_t off = 0;
  auto carve = [&](size_t bytes) {
    void* p = ws + off;
    off = (off + bytes + 255) & ~(size_t)255;
    return p;
  };
  float* x      = (float*)carve((size_t)EE * DIN * 4);   // 163.8 MB
  float* er     = (float*)carve((size_t)NN * KK * 4);    // 0.64 MB
  float* V      = (float*)carve((size_t)DIN * KK * 4);   // 4 KB
  float* e_log  = (float*)carve((size_t)EE * KK * 4);    // 10.2 MB
  int*   counts = (int*)carve((size_t)NN * 4);
  int*   offs   = (int*)carve((size_t)(NN + 1) * 4);
  int*   cursor = (int*)carve((size_t)NN * 4);
  int*   elist  = (int*)carve((size_t)EE * 4);           // 1.28 MB
  float* y      = (float*)carve((size_t)NN * KK * DIN * 4);  // 81.9 MB
  (void)ws_size; (void)in_sizes; (void)n_in; (void)out_size;

  hipMemsetAsync(counts, 0, (size_t)NN * 4, stream);

  k_v  <<<4, 256, 0, stream>>>(W_enc, attn_l, V);
  k_er <<<(NN * KK) / 256, 256, 0, stream>>>(node_feat, W_r, er);
  k_mean_logits<<<EE / 16, 256, 0, stream>>>(edge_feat, V, er, dst, x, e_log);
  k_hist<<<EE / 256, 256, 0, stream>>>(dst, counts);
  k_scan<<<1, 1024, 0, stream>>>(counts, offs, cursor);
  k_fill<<<EE / 256, 256, 0, stream>>>(dst, cursor, elist);
  k_agg <<<NN, 256, 0, stream>>>(offs, elist, e_log, x, y);
  k_out <<<dim3(NN / 32, KK), 256, 0, stream>>>(y, W_enc, out);
}

// Round 2
// 867.252 us; speedup vs baseline: 1.1005x; 1.1005x over previous
//
#include <hip/hip_runtime.h>
#include <math.h>

// Problem constants (fixed by the reference)
#define NN   20000
#define EE   320000
#define DIN  128
#define KK   8
#define HH   64
#define NEG  0.01f

typedef __attribute__((ext_vector_type(8))) short short8;   // 8 bf16 (4 VGPRs)
typedef __attribute__((ext_vector_type(4))) float f32x4;    // MFMA acc

// ---------------------------------------------------------------------------
// bf16 helpers (RNE)
// ---------------------------------------------------------------------------
__device__ __forceinline__ unsigned short f2bf(float f) {
  unsigned u = __float_as_uint(f);
  u += 0x7FFF + ((u >> 16) & 1);
  return (unsigned short)(u >> 16);
}
__device__ __forceinline__ float bf2f_lo(unsigned u) {  // low 16 bits
  return __uint_as_float(u << 16);
}
__device__ __forceinline__ float bf2f_hi(unsigned u) {  // high 16 bits
  return __uint_as_float(u & 0xFFFF0000u);
}

__device__ __forceinline__ float wave_sum(float v) {
#pragma unroll
  for (int m = 1; m < 64; m <<= 1) v += __shfl_xor(v, m, 64);
  return v;
}

// ---------------------------------------------------------------------------
// K-prep A: Vt[n][d] (bf16, n in [0,16), rows of 128) = sum_h W_enc[d,n*64+h]*attn_l[n,h]
// n >= 8 rows are zero (MFMA N-pad).
// ---------------------------------------------------------------------------
__global__ __launch_bounds__(256) void k_vt(const float* __restrict__ W_enc,
                                            const float* __restrict__ attn_l,
                                            unsigned short* __restrict__ Vt) {
  int gid = blockIdx.x * 256 + threadIdx.x;  // 2048
  if (gid >= 16 * 128) return;
  int n = gid >> 7, d = gid & 127;
  float acc = 0.f;
  if (n < 8) {
#pragma unroll 8
    for (int h = 0; h < HH; ++h)
      acc += W_enc[(size_t)d * 512 + n * 64 + h] * attn_l[n * 64 + h];
  }
  Vt[gid] = f2bf(acc);
}

// ---------------------------------------------------------------------------
// K-prep B: Wt[kh*64+h][d] (bf16) = W_enc[d][kh*64+h]  (transposed for MFMA B)
// ---------------------------------------------------------------------------
__global__ __launch_bounds__(256) void k_wt(const float* __restrict__ W_enc,
                                            unsigned short* __restrict__ Wt) {
  int gid = blockIdx.x * 256 + threadIdx.x;  // 65536
  int row = gid >> 7, d = gid & 127;         // row = kh*64+h
  Wt[gid] = f2bf(W_enc[(size_t)d * 512 + row]);
}

// ---------------------------------------------------------------------------
// K1: er[n][k] = node_feat[n,:] . W_r[k,:]   (fp32)
// ---------------------------------------------------------------------------
__global__ __launch_bounds__(256) void k_er(const float* __restrict__ node_feat,
                                            const float* __restrict__ W_r,
                                            float* __restrict__ er) {
  __shared__ __align__(16) float4 wr4[KK * 32];
  int tid = threadIdx.x;
  if (tid < 256) wr4[tid] = ((const float4*)W_r)[tid];
  __syncthreads();
  int gid = blockIdx.x * 256 + tid;
  int n = gid >> 3, k = gid & 7;
  if (n < NN) {
    const float4* nf4 = (const float4*)node_feat + (size_t)n * 32;
    float acc = 0.f;
#pragma unroll
    for (int i = 0; i < 32; ++i) {
      float4 a = nf4[i], b = wr4[k * 32 + i];
      acc += a.x * b.x + a.y * b.y + a.z * b.z + a.w * b.w;
    }
    er[gid] = acc;
  }
}

// ---------------------------------------------------------------------------
// K2: pure streaming mean:  x_bf16[e][d] = mean_L edge_feat[e][l][d]
// thread owns 8 floats of one edge. 573 MB total traffic -> BW-bound.
// ---------------------------------------------------------------------------
__global__ __launch_bounds__(256) void k_mean(const float* __restrict__ ef,
                                              unsigned short* __restrict__ x) {
  size_t gid = (size_t)blockIdx.x * 256 + threadIdx.x;  // E*16 = 5.12M
  size_t e = gid >> 4;
  int s = gid & 15;
  const float4* p = (const float4*)(ef + e * 384) + s * 2;
  float4 a0 = p[0],  a1 = p[1];
  float4 b0 = p[32], b1 = p[33];
  float4 c0 = p[64], c1 = p[65];
  const float i3 = 1.f / 3.f;
  float m0 = (a0.x + b0.x + c0.x) * i3, m1 = (a0.y + b0.y + c0.y) * i3;
  float m2 = (a0.z + b0.z + c0.z) * i3, m3 = (a0.w + b0.w + c0.w) * i3;
  float m4 = (a1.x + b1.x + c1.x) * i3, m5 = (a1.y + b1.y + c1.y) * i3;
  float m6 = (a1.z + b1.z + c1.z) * i3, m7 = (a1.w + b1.w + c1.w) * i3;
  uint4 o;
  o.x = (unsigned)f2bf(m0) | ((unsigned)f2bf(m1) << 16);
  o.y = (unsigned)f2bf(m2) | ((unsigned)f2bf(m3) << 16);
  o.z = (unsigned)f2bf(m4) | ((unsigned)f2bf(m5) << 16);
  o.w = (unsigned)f2bf(m6) | ((unsigned)f2bf(m7) << 16);
  ((uint4*)x)[gid] = o;
}

// ---------------------------------------------------------------------------
// K3: logits via MFMA. One wave = 16 edges. el = x @ V (K=128 via 4 mfma),
// then + er[dst], leaky, store e_log. dst histogram fused (col==0 lanes).
// ---------------------------------------------------------------------------
__global__ __launch_bounds__(256) void k_logit(const unsigned short* __restrict__ x,
                                               const unsigned short* __restrict__ Vt,
                                               const float* __restrict__ er,
                                               const int* __restrict__ dst,
                                               float* __restrict__ e_log,
                                               int* __restrict__ counts) {
  int lane = threadIdx.x & 63;
  int gw = (blockIdx.x * 256 + (int)threadIdx.x) >> 6;
  int e0 = gw * 16;
  int m = lane & 15, quad = lane >> 4;
  const short8* xr = (const short8*)(x + (size_t)(e0 + m) * 128);
  const short8* vr = (const short8*)(Vt + (size_t)m * 128);
  f32x4 acc = {0.f, 0.f, 0.f, 0.f};
#pragma unroll
  for (int kt = 0; kt < 4; ++kt) {
    short8 a = xr[kt * 4 + quad];   // A[m=edge][k=kt*32+quad*8+j]
    short8 b = vr[kt * 4 + quad];   // B[k][n=m] from transposed Vt
    acc = __builtin_amdgcn_mfma_f32_16x16x32_bf16(a, b, acc, 0, 0, 0);
  }
  // C layout: col = lane&15 (k-head), row = quad*4 + r (edge)
  if (m < 8) {
#pragma unroll
    for (int r = 0; r < 4; ++r) {
      int e = e0 + quad * 4 + r;
      int dv = dst[e];
      float z = acc[r] + er[dv * 8 + m];
      z = z > 0.f ? z : NEG * z;
      e_log[(size_t)e * 8 + m] = z;
      if (m == 0) atomicAdd(&counts[dv], 1);
    }
  }
}

// ---------------------------------------------------------------------------
// Hierarchical exclusive scan (3 kernels)
// ---------------------------------------------------------------------------
__device__ __forceinline__ int block_excl_scan256(int v, int tid) {
  __shared__ int wtot[4];
  int lane = tid & 63, wid = tid >> 6;
  int incl = v;
#pragma unroll
  for (int off = 1; off < 64; off <<= 1) {
    int t = __shfl_up(incl, off, 64);
    if (lane >= off) incl += t;
  }
  if (lane == 63) wtot[wid] = incl;
  __syncthreads();
  if (tid == 0) {
    int s = 0;
#pragma unroll
    for (int i = 0; i < 4; ++i) { int t = wtot[i]; wtot[i] = s; s += t; }
  }
  __syncthreads();
  return wtot[wid] + incl - v;
}

__global__ __launch_bounds__(256) void k_scan1(const int* __restrict__ counts,
                                               int* __restrict__ lexcl,
                                               int* __restrict__ btot) {
  int b = blockIdx.x, tid = threadIdx.x;
  int i = b * 256 + tid;
  int v = (i < NN) ? counts[i] : 0;
  int ex = block_excl_scan256(v, tid);
  lexcl[i] = ex;
  if (tid == 255) btot[b] = ex + v;
}

__global__ __launch_bounds__(256) void k_scan2(int* __restrict__ btot,
                                               int* __restrict__ bbase,
                                               int* __restrict__ offs) {
  int tid = threadIdx.x;
  int v = (tid < 80) ? btot[tid] : 0;
  int ex = block_excl_scan256(v, tid);
  if (tid < 80) bbase[tid] = ex;
  if (tid == 0) offs[NN] = EE;  // grand total is exactly E
}

__global__ __launch_bounds__(256) void k_scan3(const int* __restrict__ lexcl,
                                               const int* __restrict__ bbase,
                                               int* __restrict__ offs,
                                               int* __restrict__ cursor) {
  int b = blockIdx.x, tid = threadIdx.x;
  int i = b * 256 + tid;
  if (i < NN) {
    int o = lexcl[i] + bbase[b];
    offs[i] = o;
    cursor[i] = o;
  }
}

// ---------------------------------------------------------------------------
// K5: scatter edge ids into CSR
// ---------------------------------------------------------------------------
__global__ __launch_bounds__(256) void k_fill(const int* __restrict__ dst,
                                              int* __restrict__ cursor,
                                              int* __restrict__ elist) {
  int e = blockIdx.x * 256 + threadIdx.x;
  if (e < EE) {
    int p = atomicAdd(&cursor[dst[e]], 1);
    elist[p] = e;
  }
}

// ---------------------------------------------------------------------------
// K6: per-node segmented softmax + weighted aggregation:
//     y_bf16[n,k,d] = sum_{e in n} a[e,k] * x[e,d]
// ---------------------------------------------------------------------------
__global__ __launch_bounds__(256) void k_agg(const int* __restrict__ offs,
                                             const int* __restrict__ elist,
                                             const float* __restrict__ e_log,
                                             const unsigned short* __restrict__ x,
                                             unsigned short* __restrict__ y) {
  __shared__ float maxs[8], invs[8];
  __shared__ float red[4][8];
  __shared__ __align__(16) float xs[32 * 128];  // 16 KB, fp32-unpacked tiles
  __shared__ __align__(16) float wbuf[32 * 8];
  int n = blockIdx.x;
  int tid = threadIdx.x, lane = tid & 63, wid = tid >> 6;
  int start = offs[n], end = offs[n + 1];

  // ---- pass A: per-k max ----
  float m[8];
#pragma unroll
  for (int k = 0; k < 8; ++k) m[k] = -3.4e38f;
  for (int i = start + tid; i < end; i += 256) {
    size_t e = (size_t)elist[i];
    float4 a = ((const float4*)e_log)[e * 2 + 0];
    float4 b = ((const float4*)e_log)[e * 2 + 1];
    m[0] = fmaxf(m[0], a.x); m[1] = fmaxf(m[1], a.y);
    m[2] = fmaxf(m[2], a.z); m[3] = fmaxf(m[3], a.w);
    m[4] = fmaxf(m[4], b.x); m[5] = fmaxf(m[5], b.y);
    m[6] = fmaxf(m[6], b.z); m[7] = fmaxf(m[7], b.w);
  }
#pragma unroll
  for (int k = 0; k < 8; ++k) {
#pragma unroll
    for (int mm = 1; mm < 64; mm <<= 1) m[k] = fmaxf(m[k], __shfl_xor(m[k], mm, 64));
  }
  if (lane == 0) {
#pragma unroll
    for (int k = 0; k < 8; ++k) red[wid][k] = m[k];
  }
  __syncthreads();
  if (tid < 8)
    maxs[tid] = fmaxf(fmaxf(red[0][tid], red[1][tid]), fmaxf(red[2][tid], red[3][tid]));
  __syncthreads();
  float mk[8];
#pragma unroll
  for (int k = 0; k < 8; ++k) mk[k] = maxs[k];

  // ---- pass B: per-k sum of exp ----
  float s[8];
#pragma unroll
  for (int k = 0; k < 8; ++k) s[k] = 0.f;
  for (int i = start + tid; i < end; i += 256) {
    size_t e = (size_t)elist[i];
    float4 a = ((const float4*)e_log)[e * 2 + 0];
    float4 b = ((const float4*)e_log)[e * 2 + 1];
    s[0] += __expf(a.x - mk[0]); s[1] += __expf(a.y - mk[1]);
    s[2] += __expf(a.z - mk[2]); s[3] += __expf(a.w - mk[3]);
    s[4] += __expf(b.x - mk[4]); s[5] += __expf(b.y - mk[5]);
    s[6] += __expf(b.z - mk[6]); s[7] += __expf(b.w - mk[7]);
  }
#pragma unroll
  for (int k = 0; k < 8; ++k) s[k] = wave_sum(s[k]);
  if (lane == 0) {
#pragma unroll
    for (int k = 0; k < 8; ++k) red[wid][k] = s[k];
  }
  __syncthreads();
  if (tid < 8) {
    float tot = red[0][tid] + red[1][tid] + red[2][tid] + red[3][tid];
    invs[tid] = tot > 0.f ? 1.f / tot : 0.f;
  }
  __syncthreads();

  // ---- pass C: weighted aggregation, 32-edge batches staged in LDS ----
  float acc0 = 0.f, acc1 = 0.f, acc2 = 0.f, acc3 = 0.f;
  int d = tid & 127, kg = tid >> 7;  // kg in {0,1}: k = kg*4 + i
  for (int base = start; base < end; base += 32) {
    int nb = min(32, end - base);
    for (int j = tid; j < nb * 16; j += 256) {
      size_t e = (size_t)elist[base + (j >> 4)];
      uint4 t = ((const uint4*)x)[e * 16 + (j & 15)];
      float4 lo = make_float4(bf2f_lo(t.x), bf2f_hi(t.x), bf2f_lo(t.y), bf2f_hi(t.y));
      float4 hi = make_float4(bf2f_lo(t.z), bf2f_hi(t.z), bf2f_lo(t.w), bf2f_hi(t.w));
      ((float4*)xs)[(j >> 4) * 32 + (j & 15) * 2 + 0] = lo;
      ((float4*)xs)[(j >> 4) * 32 + (j & 15) * 2 + 1] = hi;
    }
    if (tid < nb * 8) {
      size_t e = (size_t)elist[base + (tid >> 3)];
      int k = tid & 7;
      wbuf[tid] = __expf(e_log[e * 8 + k] - maxs[k]) * invs[k];
    }
    __syncthreads();
    for (int j = 0; j < nb; ++j) {
      float xv = xs[j * 128 + d];
      float4 wv = *(const float4*)&wbuf[j * 8 + kg * 4];
      acc0 += wv.x * xv; acc1 += wv.y * xv; acc2 += wv.z * xv; acc3 += wv.w * xv;
    }
    __syncthreads();
  }
  size_t yb = ((size_t)n * 8 + kg * 4) * 128 + d;
  y[yb + 0 * 128] = f2bf(acc0);
  y[yb + 1 * 128] = f2bf(acc1);
  y[yb + 2 * 128] = f2bf(acc2);
  y[yb + 3 * 128] = f2bf(acc3);
}

// ---------------------------------------------------------------------------
// K7: out[n, kh*64+h] = y[n,kh,:] @ Wt[kh*64+h,:]  via MFMA.
// Block: 16 nodes x 64 h for one kh; wave w owns h-tile w.
// ---------------------------------------------------------------------------
__global__ __launch_bounds__(256) void k_out(const unsigned short* __restrict__ y,
                                             const unsigned short* __restrict__ Wt,
                                             float* __restrict__ out) {
  int kh = blockIdx.y;
  int n0 = blockIdx.x * 16;
  int wv = threadIdx.x >> 6;
  int lane = threadIdx.x & 63;
  int m = lane & 15, quad = lane >> 4;
  int h0 = wv * 16;
  const short8* ar = (const short8*)(y + ((size_t)(n0 + m) * 8 + kh) * 128);
  const short8* br = (const short8*)(Wt + (size_t)(kh * 64 + h0 + m) * 128);
  f32x4 acc = {0.f, 0.f, 0.f, 0.f};
#pragma unroll
  for (int kt = 0; kt < 4; ++kt) {
    short8 a = ar[kt * 4 + quad];
    short8 b = br[kt * 4 + quad];
    acc = __builtin_amdgcn_mfma_f32_16x16x32_bf16(a, b, acc, 0, 0, 0);
  }
#pragma unroll
  for (int r = 0; r < 4; ++r)
    out[(size_t)(n0 + quad * 4 + r) * 512 + kh * 64 + h0 + m] = acc[r];
}

// ---------------------------------------------------------------------------
// launch
// ---------------------------------------------------------------------------
extern "C" void kernel_launch(void* const* d_in, const int* in_sizes, int n_in,
                              void* d_out, int out_size, void* d_ws, size_t ws_size,
                              hipStream_t stream) {
  const float* node_feat = (const float*)d_in[0];
  const float* edge_feat = (const float*)d_in[1];
  const float* W_enc     = (const float*)d_in[2];
  const float* attn_l    = (const float*)d_in[3];
  const float* W_r       = (const float*)d_in[4];
  const int*   dst       = (const int*)d_in[5];
  float* out = (float*)d_out;

  char* ws = (char*)d_ws;
  size_t off = 0;
  auto carve = [&](size_t bytes) {
    void* p = ws + off;
    off = (off + bytes + 255) & ~(size_t)255;
    return p;
  };
  unsigned short* x   = (unsigned short*)carve((size_t)EE * DIN * 2);     // 81.9 MB
  unsigned short* y   = (unsigned short*)carve((size_t)NN * KK * DIN * 2);// 41.0 MB
  unsigned short* Vt  = (unsigned short*)carve(16 * 128 * 2);
  unsigned short* Wt  = (unsigned short*)carve((size_t)KK * HH * DIN * 2);// 128 KB
  float* er    = (float*)carve((size_t)NN * KK * 4);
  float* e_log = (float*)carve((size_t)EE * KK * 4);                       // 10.2 MB
  int* counts  = (int*)carve((size_t)20480 * 4);
  int* lexcl   = (int*)carve((size_t)20480 * 4);
  int* btot    = (int*)carve(80 * 4);
  int* bbase   = (int*)carve(80 * 4);
  int* offs    = (int*)carve((size_t)(NN + 1) * 4);
  int* cursor  = (int*)carve((size_t)NN * 4);
  int* elist   = (int*)carve((size_t)EE * 4);
  (void)ws_size; (void)in_sizes; (void)n_in; (void)out_size;

  hipMemsetAsync(counts, 0, (size_t)NN * 4, stream);

  k_vt  <<<8, 256, 0, stream>>>(W_enc, attn_l, Vt);
  k_wt  <<<256, 256, 0, stream>>>(W_enc, Wt);
  k_er  <<<(NN * KK) / 256, 256, 0, stream>>>(node_feat, W_r, er);
  k_mean<<<(EE * 16) / 256, 256, 0, stream>>>(edge_feat, x);
  k_logit<<<EE / 64, 256, 0, stream>>>(x, Vt, er, dst, e_log, counts);
  k_scan1<<<80, 256, 0, stream>>>(counts, lexcl, btot);
  k_scan2<<<1, 256, 0, stream>>>(btot, bbase, offs);
  k_scan3<<<80, 256, 0, stream>>>(lexcl, bbase, offs, cursor);
  k_fill<<<EE / 256, 256, 0, stream>>>(dst, cursor, elist);
  k_agg <<<NN, 256, 0, stream>>>(offs, elist, e_log, x, y);
  k_out <<<dim3(NN / 16, KK), 256, 0, stream>>>(y, Wt, out);
}